// Round 3
// baseline (115.870 us; speedup 1.0000x reference)
//
#include <hip/hip_runtime.h>
#include <hip/hip_bf16.h>

namespace {

constexpr int kB = 8, kT = 64, kE = 4, kD = 256, kH = 1024;
constexpr int kNC = 8;             // H-chunks per (t,e)
constexpr int kHc = kH / kNC;      // 128
constexpr int kThreads = 128;

__device__ __forceinline__ float gelu_exact(float v) {
  return 0.5f * v * (1.0f + erff(v * 0.70710678118654752f));
}

__global__ __launch_bounds__(kThreads, 4)
void moe_ffn_kernel(const float* __restrict__ x,
                    const float* __restrict__ fc1,
                    const float* __restrict__ b1,
                    const float* __restrict__ fc2,
                    const float* __restrict__ b2,
                    const float* __restrict__ Wr,
                    const float* __restrict__ br,
                    float* __restrict__ out) {
  __shared__ float xs[kB][kD];     // 8 KB
  __shared__ float hid[kB][kHc];   // 4 KB
  __shared__ float gates_s[kB];

  const int tid = threadIdx.x;
  const int bid = blockIdx.x;      // te * kNC + c
  const int te  = bid / kNC;
  const int c   = bid % kNC;
  const int t   = te >> 2;
  const int h0  = c * kHc;

  // ---- stage x[b, t, :] into LDS as float4 (1 KB per wave-inst) ----
  {
    const float4* __restrict__ xsrc = reinterpret_cast<const float4*>(x);
    float4* xdst = reinterpret_cast<float4*>(&xs[0][0]);
#pragma unroll
    for (int i = 0; i < 4; ++i) {
      const int f = i * kThreads + tid;      // 0..511 float4s
      const int b = f >> 6, d4 = f & 63;
      xdst[f] = xsrc[(size_t)(b * kT + t) * (kD / 4) + d4];
    }
  }
  __syncthreads();

  const int wave = tid >> 6, lane = tid & 63;

  // ---- router gates: wave w handles b = 4w..4w+3 ----
  {
    const float* __restrict__ wr = Wr + (size_t)te * kD;
    const float w0 = wr[lane], w1 = wr[lane + 64], w2 = wr[lane + 128], w3 = wr[lane + 192];
#pragma unroll
    for (int bb = 0; bb < 4; ++bb) {
      const int b = wave * 4 + bb;
      float p = xs[b][lane] * w0 + xs[b][lane + 64] * w1 +
                xs[b][lane + 128] * w2 + xs[b][lane + 192] * w3;
#pragma unroll
      for (int off = 32; off; off >>= 1) p += __shfl_xor(p, off);
      if (lane == 0) {
        const float g = p + br[te];
        gates_s[b] = g > 0.0f ? g : 0.0f;
      }
    }
  }

  // ---- phase 1: hid[b][tid] = gelu(x . fc1[:, h0+tid] + b1) ----
  {
    const float* __restrict__ wp = fc1 + (size_t)te * kD * kH + h0 + tid;
    float acc[kB] = {0.f, 0.f, 0.f, 0.f, 0.f, 0.f, 0.f, 0.f};
#pragma unroll 2
    for (int d4 = 0; d4 < kD / 4; ++d4) {
      float4 xv[kB];
#pragma unroll
      for (int b = 0; b < kB; ++b)
        xv[b] = *reinterpret_cast<const float4*>(&xs[b][d4 * 4]);  // ds_read_b128 broadcast
      const float wa = wp[(size_t)(d4 * 4 + 0) * kH];
      const float wb = wp[(size_t)(d4 * 4 + 1) * kH];
      const float wc = wp[(size_t)(d4 * 4 + 2) * kH];
      const float wd = wp[(size_t)(d4 * 4 + 3) * kH];
#pragma unroll
      for (int b = 0; b < kB; ++b) {
        acc[b] = fmaf(xv[b].x, wa, acc[b]);
        acc[b] = fmaf(xv[b].y, wb, acc[b]);
        acc[b] = fmaf(xv[b].z, wc, acc[b]);
        acc[b] = fmaf(xv[b].w, wd, acc[b]);
      }
    }
    const float bias = b1[(size_t)te * kH + h0 + tid];
#pragma unroll
    for (int b = 0; b < kB; ++b) hid[b][tid] = gelu_exact(acc[b] + bias);
  }
  __syncthreads();   // hid + gates_s ready

  // ---- phase 2: thread owns d = 2*tid (float2 fc2 loads); sum over chunk h ----
  {
    const float2* __restrict__ wp =
        reinterpret_cast<const float2*>(fc2 + (size_t)te * kH * kD + (size_t)h0 * kD) + tid;
    float2 acc2[kB];
#pragma unroll
    for (int b = 0; b < kB; ++b) acc2[b] = make_float2(0.f, 0.f);
#pragma unroll 2
    for (int h4 = 0; h4 < kHc / 4; ++h4) {
      float4 hv[kB];
#pragma unroll
      for (int b = 0; b < kB; ++b)
        hv[b] = *reinterpret_cast<const float4*>(&hid[b][h4 * 4]);  // ds_read_b128 broadcast
      const float2 wva = wp[(size_t)(h4 * 4 + 0) * (kD / 2)];
      const float2 wvb = wp[(size_t)(h4 * 4 + 1) * (kD / 2)];
      const float2 wvc = wp[(size_t)(h4 * 4 + 2) * (kD / 2)];
      const float2 wvd = wp[(size_t)(h4 * 4 + 3) * (kD / 2)];
#pragma unroll
      for (int b = 0; b < kB; ++b) {
        acc2[b].x = fmaf(hv[b].x, wva.x, acc2[b].x);
        acc2[b].y = fmaf(hv[b].x, wva.y, acc2[b].y);
        acc2[b].x = fmaf(hv[b].y, wvb.x, acc2[b].x);
        acc2[b].y = fmaf(hv[b].y, wvb.y, acc2[b].y);
        acc2[b].x = fmaf(hv[b].z, wvc.x, acc2[b].x);
        acc2[b].y = fmaf(hv[b].z, wvc.y, acc2[b].y);
        acc2[b].x = fmaf(hv[b].w, wvd.x, acc2[b].x);
        acc2[b].y = fmaf(hv[b].w, wvd.y, acc2[b].y);
      }
    }
    const int d0 = 2 * tid;
    float2 bias2 = make_float2(0.f, 0.f);
    if (c == 0) {
      bias2.x = b2[(size_t)te * kD + d0];
      bias2.y = b2[(size_t)te * kD + d0 + 1];
    }
#pragma unroll
    for (int b = 0; b < kB; ++b) {
      const float g = gates_s[b];
      float* o = &out[((size_t)b * kT + t) * kD + d0];
      atomicAdd(o,     g * (acc2[b].x + bias2.x));
      atomicAdd(o + 1, g * (acc2[b].y + bias2.y));
    }
    if (c == 0 && tid == 0) {
      float gs = 0.f;
#pragma unroll
      for (int b = 0; b < kB; ++b) gs += gates_s[b];
      atomicAdd(&out[(size_t)kB * kT * kD], 0.01f * gs * (1.0f / (kB * kT)));
    }
  }
}

}  // namespace

extern "C" void kernel_launch(void* const* d_in, const int* in_sizes, int n_in,
                              void* d_out, int out_size, void* d_ws, size_t ws_size,
                              hipStream_t stream) {
  const float* x   = (const float*)d_in[0];
  const float* fc1 = (const float*)d_in[1];
  const float* b1  = (const float*)d_in[2];
  const float* fc2 = (const float*)d_in[3];
  const float* b2  = (const float*)d_in[4];
  const float* Wr  = (const float*)d_in[5];
  const float* br  = (const float*)d_in[6];
  float* out = (float*)d_out;

  // Zero the accumulation target every call (graph replays must be
  // deterministic; harness does not re-poison between replays).
  hipMemsetAsync(d_out, 0, (size_t)out_size * sizeof(float), stream);

  moe_ffn_kernel<<<dim3(kT * kE * kNC), dim3(kThreads), 0, stream>>>(
      x, fc1, b1, fc2, b2, Wr, br, out);
}